// Round 2
// baseline (228.458 us; speedup 1.0000x reference)
//
#include <hip/hip_runtime.h>
#include <stdint.h>

#define AS1 __attribute__((address_space(1)))
#define AS3 __attribute__((address_space(3)))

typedef int v4i __attribute__((ext_vector_type(4)));

// Problem constants (from reference)
constexpr int G = 7, B = 8, M = 512, N = 512, K = 1024;
constexpr int GBn = G * B;                       // 56
// X_ZP = -66, Y_ZP = 160 (hardcoded in reference)
// With y' = y - 128:  sum (x-X)(y-Y) = dot(x,y') - 32*rowsum_x + 66*colsum_y' - 2162688

// ws layout
constexpr size_t X8_BYTES = (size_t)GBn * M * K; // 29,360,128  packed x int8
constexpr size_t YT_BYTES = (size_t)B * N * K;   //  4,194,304  y transposed [b][n][k] int8 (y-128)
constexpr size_t RS_CNT   = (size_t)GBn * M;     // 28,672 rowsums
constexpr size_t CS_CNT   = (size_t)B * N;       //  4,096 colsums
constexpr size_t WS_NEEDED = X8_BYTES + YT_BYTES + RS_CNT * 4 + CS_CNT * 4;

// ---------------------------------------------------------------------------
// K1: transpose + pack y:  y[b][k][n] (int32, 0..255)  ->  yt[b][n][k] (int8, y-128)
// 64x64 tiles through LDS. Grid: (N/64, K/64, B), block 256.
// ---------------------------------------------------------------------------
__global__ __launch_bounds__(256) void transpose_pack_y(const int* __restrict__ y,
                                                        signed char* __restrict__ yt) {
    __shared__ unsigned char tile[64][80];       // 80 = 5*16: 16B-aligned rows, odd 16-bank phase
    int n0 = blockIdx.x * 64;
    int k0 = blockIdx.y * 64;
    int b  = blockIdx.z;
    int t  = threadIdx.x;

    // phase 1: coalesced read along n, pack low bytes (^0x80 == y-128 as i8), 16B to LDS
    int r  = t >> 2;                              // k-local 0..63
    int c0 = (t & 3) * 16;                        // n-local byte offset
    const int* src = y + ((size_t)b * K + k0 + r) * N + n0 + c0;
    uint32_t p[4];
#pragma unroll
    for (int q = 0; q < 4; ++q) {
        int4 v = ((const int4*)src)[q];
        p[q] =  (uint32_t)((v.x & 255) ^ 128)
             | ((uint32_t)((v.y & 255) ^ 128) << 8)
             | ((uint32_t)((v.z & 255) ^ 128) << 16)
             | ((uint32_t)((v.w & 255) ^ 128) << 24);
    }
    *(uint4*)&tile[r][c0] = make_uint4(p[0], p[1], p[2], p[3]);
    __syncthreads();

    // phase 2: gather a column of 16 k-bytes per thread, write 16B contiguous in k
    int nl = t >> 2;                              // n-local 0..63
    int kc = (t & 3) * 16;                        // k-local byte offset
    uint32_t q[4];
#pragma unroll
    for (int w = 0; w < 4; ++w) {
        uint32_t b0 = tile[kc + w * 4 + 0][nl];
        uint32_t b1 = tile[kc + w * 4 + 1][nl];
        uint32_t b2 = tile[kc + w * 4 + 2][nl];
        uint32_t b3 = tile[kc + w * 4 + 3][nl];
        q[w] = b0 | (b1 << 8) | (b2 << 16) | (b3 << 24);
    }
    *(uint4*)(yt + ((size_t)b * N + n0 + nl) * K + k0 + kc) = make_uint4(q[0], q[1], q[2], q[3]);
}

// ---------------------------------------------------------------------------
// K2: pack x int32 -> int8 + rowsum(x);  plus colsum(y') from yt.
// One wave per 1024-elem row. Rows 0..28671 = x rows; 28672..32767 = yt rows.
// Grid: 8192 blocks x 256 (4 waves, 4 rows/block).
// ---------------------------------------------------------------------------
__device__ __forceinline__ int wave_reduce_sum(int v) {
#pragma unroll
    for (int off = 32; off > 0; off >>= 1) v += __shfl_down(v, off, 64);
    return v;
}

__global__ __launch_bounds__(256) void pack_x_sums(const int* __restrict__ x,
                                                   signed char* __restrict__ x8,
                                                   const signed char* __restrict__ yt,
                                                   int* __restrict__ rowsum,
                                                   int* __restrict__ colsum) {
    int wave = threadIdx.x >> 6, lane = threadIdx.x & 63;
    int row = blockIdx.x * 4 + wave;
    if (row < (int)(GBn * M)) {
        const int* src = x + (size_t)row * K + lane * 16;   // 16 ints = 64B per lane
        int s = 0;
        uint32_t p[4];
#pragma unroll
        for (int q = 0; q < 4; ++q) {
            int4 v = ((const int4*)src)[q];
            s += v.x + v.y + v.z + v.w;
            p[q] =  (uint32_t)(v.x & 255)
                 | ((uint32_t)(v.y & 255) << 8)
                 | ((uint32_t)(v.z & 255) << 16)
                 | ((uint32_t)(v.w & 255) << 24);
        }
        *(uint4*)(x8 + (size_t)row * K + lane * 16) = make_uint4(p[0], p[1], p[2], p[3]);
        s = wave_reduce_sum(s);
        if (lane == 0) rowsum[row] = s;
    } else {
        int rr = row - (int)(GBn * M);                      // 0..4095  (b*N + n)
        uint4 u = *(const uint4*)(yt + (size_t)rr * K + lane * 16);
        uint32_t wds[4] = {u.x, u.y, u.z, u.w};
        int s = 0;
#pragma unroll
        for (int q = 0; q < 4; ++q) {
            uint32_t w = wds[q];
            s += (int)(signed char)(w) + (int)(signed char)(w >> 8)
               + (int)(signed char)(w >> 16) + (int)(signed char)(w >> 24);
        }
        s = wave_reduce_sum(s);
        if (lane == 0) colsum[rr] = s;
    }
}

// ---------------------------------------------------------------------------
// K3: i8 MFMA GEMM. Block = 128x128 C-tile for one (g,b). 4 waves, each 64x64
// (4x4 tiles of mfma_i32_16x16x64_i8). BK=64. m97-style global_load_lds staging.
// Grid: (16 tiles, 56 gb), block 256.
// ---------------------------------------------------------------------------
__global__ __launch_bounds__(256, 2) void gemm_i8(const signed char* __restrict__ x8,
                                                  const signed char* __restrict__ yt,
                                                  const int* __restrict__ rowsum,
                                                  const int* __restrict__ colsum,
                                                  const float* __restrict__ xsp,
                                                  const float* __restrict__ ysp,
                                                  float* __restrict__ out) {
    __shared__ signed char As[128 * 64];   // [m][k] rows of 64B
    __shared__ signed char Bs[128 * 64];   // [n][k] rows of 64B

    int tile = blockIdx.x;                 // 0..15
    int gb   = blockIdx.y;                 // 0..55
    int mt = tile >> 2, nt = tile & 3;
    int b  = gb & 7;
    int tid = threadIdx.x, wave = tid >> 6, lane = tid & 63;
    int wm = (wave >> 1) * 64, wn = (wave & 1) * 64;

    // staging: each wave stages 32 rows of A and 32 rows of B (16 rows per c-step,
    // 4 lanes x 16B per 64B row). LDS dest is wave-uniform base + lane*16.
    const signed char* Ab = x8 + ((size_t)(gb * M + mt * 128 + wave * 32 + (lane >> 2))) * K + (lane & 3) * 16;
    const signed char* Bb = yt + ((size_t)(b  * N + nt * 128 + wave * 32 + (lane >> 2))) * K + (lane & 3) * 16;
    signed char* AsW = As + wave * 2048;
    signed char* BsW = Bs + wave * 2048;

    v4i zero = {0, 0, 0, 0};
    v4i acc[4][4];
#pragma unroll
    for (int i = 0; i < 4; ++i)
#pragma unroll
        for (int j = 0; j < 4; ++j) acc[i][j] = zero;

    int fr = lane & 15;                    // row-in-tile (A) / col-in-tile (B)
    int fk = (lane >> 4) * 16;             // k byte offset for this quad

    for (int k0 = 0; k0 < K; k0 += 64) {
#pragma unroll
        for (int c = 0; c < 2; ++c) {
            __builtin_amdgcn_global_load_lds((const AS1 uint32_t*)(Ab + (size_t)c * 16 * K + k0),
                                             (AS3 uint32_t*)(AsW + c * 1024), 16, 0, 0);
            __builtin_amdgcn_global_load_lds((const AS1 uint32_t*)(Bb + (size_t)c * 16 * K + k0),
                                             (AS3 uint32_t*)(BsW + c * 1024), 16, 0, 0);
        }
        __syncthreads();

        v4i af[4], bf[4];
#pragma unroll
        for (int i = 0; i < 4; ++i)
            af[i] = *(const v4i*)(As + (wm + i * 16 + fr) * 64 + fk);
#pragma unroll
        for (int j = 0; j < 4; ++j)
            bf[j] = *(const v4i*)(Bs + (wn + j * 16 + fr) * 64 + fk);

#pragma unroll
        for (int i = 0; i < 4; ++i)
#pragma unroll
            for (int j = 0; j < 4; ++j)
                acc[i][j] = __builtin_amdgcn_mfma_i32_16x16x64_i8(af[i], bf[j], acc[i][j], 0, 0, 0);
        __syncthreads();
    }

    // epilogue: C = s * (dot - 32*rowsum_x + 66*colsum_y' - 2162688)
    float s = xsp[0] * ysp[0];
    int colL = lane & 15;
    int rowQ = (lane >> 4) * 4;
    float* outg = out + (size_t)gb * M * N;
    const int* rs = rowsum + gb * M;
    const int* cs = colsum + b * N;
#pragma unroll
    for (int i = 0; i < 4; ++i) {
#pragma unroll
        for (int r = 0; r < 4; ++r) {
            int row_g = mt * 128 + wm + i * 16 + rowQ + r;
            int rsv = rs[row_g];
#pragma unroll
            for (int j = 0; j < 4; ++j) {
                int col_g = nt * 128 + wn + j * 16 + colL;
                int t = acc[i][j][r] - 32 * rsv + 66 * cs[col_g] - 2162688;
                outg[(size_t)row_g * N + col_g] = s * (float)t;
            }
        }
    }
}

// ---------------------------------------------------------------------------
// Fallback (only if ws_size is too small): naive but correct.
// sum (x-X)(y-Y) = dot(x,y) - 160*sum_x + 66*sum_y - 10,813,440
// ---------------------------------------------------------------------------
__global__ __launch_bounds__(256) void naive_kernel(const int* __restrict__ x,
                                                    const int* __restrict__ y,
                                                    const float* __restrict__ xsp,
                                                    const float* __restrict__ ysp,
                                                    float* __restrict__ out) {
    size_t idx = (size_t)blockIdx.x * 256 + threadIdx.x;   // over 14,680,064
    int n  = (int)(idx & 511);
    int m  = (int)((idx >> 9) & 511);
    int gb = (int)(idx >> 18);
    int b  = gb & 7;
    const int* xr = x + ((size_t)gb * M + m) * K;
    const int* yc = y + (size_t)b * K * N + n;
    int dot = 0, sx = 0, sy = 0;
    for (int k = 0; k < K; ++k) {
        int a = xr[k];
        int c = yc[(size_t)k * N];
        dot += a * c; sx += a; sy += c;
    }
    float s = xsp[0] * ysp[0];
    out[idx] = s * (float)(dot - 160 * sx + 66 * sy - 10813440);
}

// ---------------------------------------------------------------------------
extern "C" void kernel_launch(void* const* d_in, const int* in_sizes, int n_in,
                              void* d_out, int out_size, void* d_ws, size_t ws_size,
                              hipStream_t stream) {
    const int*   x  = (const int*)d_in[0];     // [7,8,512,1024] int8 values in int32
    const int*   y  = (const int*)d_in[1];     // [8,1024,512] uint8 values in int32
    const float* xs = (const float*)d_in[2];
    const float* ys = (const float*)d_in[3];
    float* out = (float*)d_out;

    if (ws_size < WS_NEEDED) {
        naive_kernel<<<(14680064 + 255) / 256, 256, 0, stream>>>(x, y, xs, ys, out);
        return;
    }

    char* ws = (char*)d_ws;
    signed char* x8 = (signed char*)ws;
    signed char* yt = (signed char*)(ws + X8_BYTES);
    int* rowsum = (int*)(ws + X8_BYTES + YT_BYTES);
    int* colsum = rowsum + RS_CNT;

    transpose_pack_y<<<dim3(N / 64, K / 64, B), 256, 0, stream>>>(y, yt);
    // 32768 rows total (28672 x-rows + 4096 yt-rows), 4 rows per block
    pack_x_sums<<<(GBn * M + CS_CNT) / 4, 256, 0, stream>>>(x, x8, yt, rowsum, colsum);
    gemm_i8<<<dim3(16, GBn), 256, 0, stream>>>(x8, yt, rowsum, colsum, xs, ys, out);
}

// Round 3
// 227.254 us; speedup vs baseline: 1.0053x; 1.0053x over previous
//
#include <hip/hip_runtime.h>
#include <stdint.h>

#define AS1 __attribute__((address_space(1)))
#define AS3 __attribute__((address_space(3)))

typedef int v4i __attribute__((ext_vector_type(4)));

// Problem constants (from reference)
constexpr int G = 7, B = 8, M = 512, N = 512, K = 1024;
constexpr int GBn = G * B;                       // 56
// X_ZP = -66, Y_ZP = 160 (hardcoded in reference)
// With y' = y - 128:  sum (x-X)(y-Y) = dot(x,y') - 32*rowsum_x + 66*colsum_y' - 2162688

// ws layout
constexpr size_t X8_BYTES = (size_t)GBn * M * K; // 29,360,128  packed x int8
constexpr size_t YT_BYTES = (size_t)B * N * K;   //  4,194,304  y transposed [b][n][k] int8 (y-128)
constexpr size_t RS_CNT   = (size_t)GBn * M;     // 28,672 rowsums
constexpr size_t CS_CNT   = (size_t)B * N;       //  4,096 colsums
constexpr size_t WS_NEEDED = X8_BYTES + YT_BYTES + RS_CNT * 4 + CS_CNT * 4;

// ---------------------------------------------------------------------------
// K1: transpose + pack y:  y[b][k][n] (int32, 0..255)  ->  yt[b][n][k] (int8, y-128)
// 64x64 tiles through LDS. Grid: (N/64, K/64, B), block 256.
// ---------------------------------------------------------------------------
__global__ __launch_bounds__(256) void transpose_pack_y(const int* __restrict__ y,
                                                        signed char* __restrict__ yt) {
    __shared__ unsigned char tile[64][80];       // 80 = 5*16: 16B-aligned rows, odd 16-bank phase
    int n0 = blockIdx.x * 64;
    int k0 = blockIdx.y * 64;
    int b  = blockIdx.z;
    int t  = threadIdx.x;

    // phase 1: coalesced read along n, pack low bytes (^0x80 == y-128 as i8), 16B to LDS
    int r  = t >> 2;                              // k-local 0..63
    int c0 = (t & 3) * 16;                        // n-local byte offset
    const int* src = y + ((size_t)b * K + k0 + r) * N + n0 + c0;
    uint32_t p[4];
#pragma unroll
    for (int q = 0; q < 4; ++q) {
        int4 v = ((const int4*)src)[q];
        p[q] =  (uint32_t)((v.x & 255) ^ 128)
             | ((uint32_t)((v.y & 255) ^ 128) << 8)
             | ((uint32_t)((v.z & 255) ^ 128) << 16)
             | ((uint32_t)((v.w & 255) ^ 128) << 24);
    }
    *(uint4*)&tile[r][c0] = make_uint4(p[0], p[1], p[2], p[3]);
    __syncthreads();

    // phase 2: gather a column of 16 k-bytes per thread, write 16B contiguous in k
    int nl = t >> 2;                              // n-local 0..63
    int kc = (t & 3) * 16;                        // k-local byte offset
    uint32_t q[4];
#pragma unroll
    for (int w = 0; w < 4; ++w) {
        uint32_t b0 = tile[kc + w * 4 + 0][nl];
        uint32_t b1 = tile[kc + w * 4 + 1][nl];
        uint32_t b2 = tile[kc + w * 4 + 2][nl];
        uint32_t b3 = tile[kc + w * 4 + 3][nl];
        q[w] = b0 | (b1 << 8) | (b2 << 16) | (b3 << 24);
    }
    *(uint4*)(yt + ((size_t)b * N + n0 + nl) * K + k0 + kc) = make_uint4(q[0], q[1], q[2], q[3]);
}

// ---------------------------------------------------------------------------
// K2: pack x int32 -> int8 + rowsum(x);  plus colsum(y') from yt.
// One wave per 1024-elem row. Rows 0..28671 = x rows; 28672..32767 = yt rows.
// Grid: 8192 blocks x 256 (4 waves, 4 rows/block).
// ---------------------------------------------------------------------------
__device__ __forceinline__ int wave_reduce_sum(int v) {
#pragma unroll
    for (int off = 32; off > 0; off >>= 1) v += __shfl_down(v, off, 64);
    return v;
}

__global__ __launch_bounds__(256) void pack_x_sums(const int* __restrict__ x,
                                                   signed char* __restrict__ x8,
                                                   const signed char* __restrict__ yt,
                                                   int* __restrict__ rowsum,
                                                   int* __restrict__ colsum) {
    int wave = threadIdx.x >> 6, lane = threadIdx.x & 63;
    int row = blockIdx.x * 4 + wave;
    if (row < (int)(GBn * M)) {
        const int* src = x + (size_t)row * K + lane * 16;   // 16 ints = 64B per lane
        int s = 0;
        uint32_t p[4];
#pragma unroll
        for (int q = 0; q < 4; ++q) {
            int4 v = ((const int4*)src)[q];
            s += v.x + v.y + v.z + v.w;
            p[q] =  (uint32_t)(v.x & 255)
                 | ((uint32_t)(v.y & 255) << 8)
                 | ((uint32_t)(v.z & 255) << 16)
                 | ((uint32_t)(v.w & 255) << 24);
        }
        *(uint4*)(x8 + (size_t)row * K + lane * 16) = make_uint4(p[0], p[1], p[2], p[3]);
        s = wave_reduce_sum(s);
        if (lane == 0) rowsum[row] = s;
    } else {
        int rr = row - (int)(GBn * M);                      // 0..4095  (b*N + n)
        uint4 u = *(const uint4*)(yt + (size_t)rr * K + lane * 16);
        uint32_t wds[4] = {u.x, u.y, u.z, u.w};
        int s = 0;
#pragma unroll
        for (int q = 0; q < 4; ++q) {
            uint32_t w = wds[q];
            s += (int)(signed char)(w) + (int)(signed char)(w >> 8)
               + (int)(signed char)(w >> 16) + (int)(signed char)(w >> 24);
        }
        s = wave_reduce_sum(s);
        if (lane == 0) colsum[rr] = s;
    }
}

// ---------------------------------------------------------------------------
// K3: i8 MFMA GEMM. Block = 128x128 C-tile for one (g,b). 4 waves, each 64x64
// (4x4 tiles of mfma_i32_16x16x64_i8). BK=64, global_load_lds staging.
//
// LDS bank-conflict swizzle: physical 16B slot p within each 64B row holds
// global k-chunk  s = p ^ ((lds_row>>1)&3).  Implemented on the STAGE side
// (global_load_lds dest is fixed at base+lane*16) by permuting which chunk
// each lane fetches; readers compute p = want_slot ^ ((row>>1)&3).
// Result: per quad, 16 rows spread over 8 bank-groups x 2 lanes (2-way = free)
// instead of 2 bank-groups x 8 lanes (8-way, ~2.9x).
// Grid: (16 tiles, 56 gb), block 256.
// ---------------------------------------------------------------------------
__global__ __launch_bounds__(256, 2) void gemm_i8(const signed char* __restrict__ x8,
                                                  const signed char* __restrict__ yt,
                                                  const int* __restrict__ rowsum,
                                                  const int* __restrict__ colsum,
                                                  const float* __restrict__ xsp,
                                                  const float* __restrict__ ysp,
                                                  float* __restrict__ out) {
    __shared__ signed char As[128 * 64];   // [m][k] rows of 64B, k-slots swizzled
    __shared__ signed char Bs[128 * 64];   // [n][k] rows of 64B, k-slots swizzled

    int tile = blockIdx.x;                 // 0..15
    int gb   = blockIdx.y;                 // 0..55
    int mt = tile >> 2, nt = tile & 3;
    int b  = gb & 7;
    int tid = threadIdx.x, wave = tid >> 6, lane = tid & 63;
    int wm = (wave >> 1) * 64, wn = (wave & 1) * 64;

    // staging: each wave stages 32 rows of A and 32 rows of B (16 rows per
    // c-step, 4 lanes x 16B per 64B row). Source chunk is swizzled; the 4
    // lanes of a row still cover the same 64B line (coalescing unchanged).
    int srow  = lane >> 2;                             // row within 16-row c-step
    int sslot = (lane & 3) ^ ((lane >> 3) & 3);        // swizzled k-chunk
    const signed char* Ab = x8 + ((size_t)(gb * M + mt * 128 + wave * 32 + srow)) * K + sslot * 16;
    const signed char* Bb = yt + ((size_t)(b  * N + nt * 128 + wave * 32 + srow)) * K + sslot * 16;
    signed char* AsW = As + wave * 2048;
    signed char* BsW = Bs + wave * 2048;

    v4i zero = {0, 0, 0, 0};
    v4i acc[4][4];
#pragma unroll
    for (int i = 0; i < 4; ++i)
#pragma unroll
        for (int j = 0; j < 4; ++j) acc[i][j] = zero;

    int fr = lane & 15;                    // row-in-tile (A) / col-in-tile (B)
    // swizzled slot for this lane's k-quad: p = (lane>>4) ^ ((fr>>1)&3)
    int fk = ((lane >> 4) ^ ((fr >> 1) & 3)) * 16;

    for (int k0 = 0; k0 < K; k0 += 64) {
#pragma unroll
        for (int c = 0; c < 2; ++c) {
            __builtin_amdgcn_global_load_lds((const AS1 uint32_t*)(Ab + (size_t)c * 16 * K + k0),
                                             (AS3 uint32_t*)(AsW + c * 1024), 16, 0, 0);
            __builtin_amdgcn_global_load_lds((const AS1 uint32_t*)(Bb + (size_t)c * 16 * K + k0),
                                             (AS3 uint32_t*)(BsW + c * 1024), 16, 0, 0);
        }
        __syncthreads();

        v4i af[4], bf[4];
#pragma unroll
        for (int i = 0; i < 4; ++i)
            af[i] = *(const v4i*)(As + (wm + i * 16 + fr) * 64 + fk);
#pragma unroll
        for (int j = 0; j < 4; ++j)
            bf[j] = *(const v4i*)(Bs + (wn + j * 16 + fr) * 64 + fk);

#pragma unroll
        for (int i = 0; i < 4; ++i)
#pragma unroll
            for (int j = 0; j < 4; ++j)
                acc[i][j] = __builtin_amdgcn_mfma_i32_16x16x64_i8(af[i], bf[j], acc[i][j], 0, 0, 0);
        __syncthreads();
    }

    // epilogue: C = s * (dot - 32*rowsum_x + 66*colsum_y' - 2162688)
    float s = xsp[0] * ysp[0];
    int colL = lane & 15;
    int rowQ = (lane >> 4) * 4;
    float* outg = out + (size_t)gb * M * N;
    const int* rs = rowsum + gb * M;
    const int* cs = colsum + b * N;
#pragma unroll
    for (int i = 0; i < 4; ++i) {
#pragma unroll
        for (int r = 0; r < 4; ++r) {
            int row_g = mt * 128 + wm + i * 16 + rowQ + r;
            int rsv = rs[row_g];
#pragma unroll
            for (int j = 0; j < 4; ++j) {
                int col_g = nt * 128 + wn + j * 16 + colL;
                int t = acc[i][j][r] - 32 * rsv + 66 * cs[col_g] - 2162688;
                outg[(size_t)row_g * N + col_g] = s * (float)t;
            }
        }
    }
}

// ---------------------------------------------------------------------------
// Fallback (only if ws_size is too small): naive but correct.
// sum (x-X)(y-Y) = dot(x,y) - 160*sum_x + 66*sum_y - 10,813,440
// ---------------------------------------------------------------------------
__global__ __launch_bounds__(256) void naive_kernel(const int* __restrict__ x,
                                                    const int* __restrict__ y,
                                                    const float* __restrict__ xsp,
                                                    const float* __restrict__ ysp,
                                                    float* __restrict__ out) {
    size_t idx = (size_t)blockIdx.x * 256 + threadIdx.x;   // over 14,680,064
    int n  = (int)(idx & 511);
    int m  = (int)((idx >> 9) & 511);
    int gb = (int)(idx >> 18);
    int b  = gb & 7;
    const int* xr = x + ((size_t)gb * M + m) * K;
    const int* yc = y + (size_t)b * K * N + n;
    int dot = 0, sx = 0, sy = 0;
    for (int k = 0; k < K; ++k) {
        int a = xr[k];
        int c = yc[(size_t)k * N];
        dot += a * c; sx += a; sy += c;
    }
    float s = xsp[0] * ysp[0];
    out[idx] = s * (float)(dot - 160 * sx + 66 * sy - 10813440);
}

// ---------------------------------------------------------------------------
extern "C" void kernel_launch(void* const* d_in, const int* in_sizes, int n_in,
                              void* d_out, int out_size, void* d_ws, size_t ws_size,
                              hipStream_t stream) {
    const int*   x  = (const int*)d_in[0];     // [7,8,512,1024] int8 values in int32
    const int*   y  = (const int*)d_in[1];     // [8,1024,512] uint8 values in int32
    const float* xs = (const float*)d_in[2];
    const float* ys = (const float*)d_in[3];
    float* out = (float*)d_out;

    if (ws_size < WS_NEEDED) {
        naive_kernel<<<(14680064 + 255) / 256, 256, 0, stream>>>(x, y, xs, ys, out);
        return;
    }

    char* ws = (char*)d_ws;
    signed char* x8 = (signed char*)ws;
    signed char* yt = (signed char*)(ws + X8_BYTES);
    int* rowsum = (int*)(ws + X8_BYTES + YT_BYTES);
    int* colsum = rowsum + RS_CNT;

    transpose_pack_y<<<dim3(N / 64, K / 64, B), 256, 0, stream>>>(y, yt);
    // 32768 rows total (28672 x-rows + 4096 yt-rows), 4 rows per block
    pack_x_sums<<<(GBn * M + CS_CNT) / 4, 256, 0, stream>>>(x, x8, yt, rowsum, colsum);
    gemm_i8<<<dim3(16, GBn), 256, 0, stream>>>(x8, yt, rowsum, colsum, xs, ys, out);
}